// Round 1
// 238.580 us; speedup vs baseline: 1.0933x; 1.0933x over previous
//
#include <hip/hip_runtime.h>

#define EPS 1e-4f

constexpr int B = 2048;
constexpr int D = 3706;          // even -> column pairs never straddle rows
constexpr int NP = B * D / 2;    // 3,794,944 = 14824 * 256 exactly
constexpr int BLK = 256;

// Per-element bucketize. Boundaries are computed in the reference's exact
// fp32 order: step_k = max(L_k,0) + EPS first, then sequential cumsum adds.
__device__ __forceinline__ void bucketize(float a, float mb, float4 L,
                                          float* __restrict__ r6, float& v) {
    const float s0 = fmaxf(L.x, 0.0f) + EPS;
    const float s1 = fmaxf(L.y, 0.0f) + EPS;
    const float s2 = fmaxf(L.z, 0.0f) + EPS;
    const float s3 = fmaxf(L.w, 0.0f) + EPS;
    const float b0 = mb;
    const float b1 = b0 + s0;
    const float b2 = b1 + s1;
    const float b3 = b2 + s2;
    const float b4 = b3 + s3;

    // b is strictly increasing (steps >= EPS > 0), so {k : a > b_k} is a prefix.
    const int cnt = (int)(a > b0) + (int)(a > b1) + (int)(a > b2)
                  + (int)(a > b3) + (int)(a > b4);
    // heaviside(0)=0: if a equals any boundary, every dist entry is 0.
    const bool eq = (a == b0) | (a == b1) | (a == b2) | (a == b3) | (a == b4);
    const float ok = eq ? 0.0f : 1.0f;

#pragma unroll
    for (int r = 0; r < 6; ++r) r6[r] = (r == cnt) ? ok : 0.0f;
    v = eq ? 0.0f : (float)cnt;
}

__global__ __launch_bounds__(256) void disc_kernel(
        const float* __restrict__ fake,
        const float* __restrict__ minb,
        const float* __restrict__ lens,
        float* __restrict__ out) {
    // Staging for this block's dist tile: 512 elements * 6 floats = 3072 floats
    // = 768 float4 = 12 KB. Enables fully coalesced global stores.
    __shared__ float4 sd[3 * BLK];

    const int t = threadIdx.x;
    const int p = blockIdx.x * BLK + t;             // pair index (grid exact, p < NP)
    const int flat = p << 1;                        // even flat element index
    const int d0 = flat % D;                        // even column index

    const float2 a2 = reinterpret_cast<const float2*>(fake)[p];
    const float2 mb = *reinterpret_cast<const float2*>(minb + d0);
    const float4 L0 = reinterpret_cast<const float4*>(lens)[d0];
    const float4 L1 = reinterpret_cast<const float4*>(lens)[d0 + 1];

    float r0[6], r1[6], v0, v1;
    bucketize(a2.x, mb.x, L0, r0, v0);
    bucketize(a2.y, mb.y, L1, r1, v1);

    // Thread t's 12 dist floats land at block-local float offset t*12
    // (= float4 index t*3). Stride-3 float4 per lane distributes uniformly
    // over the 8 four-bank groups (gcd(3,8)=1) -> no serializing conflicts.
    sd[t * 3 + 0] = make_float4(r0[0], r0[1], r0[2], r0[3]);
    sd[t * 3 + 1] = make_float4(r0[4], r0[5], r1[0], r1[1]);
    sd[t * 3 + 2] = make_float4(r1[2], r1[3], r1[4], r1[5]);

    // val: already coalesced (8B/lane, consecutive). Issue before the barrier
    // so it overlaps the LDS round-trip.
    float* val = out + (size_t)B * D * 6;
    reinterpret_cast<float2*>(val)[p] = make_float2(v0, v1);

    __syncthreads();

    // Block's dist region = 3072 consecutive floats at out + blockIdx*3072.
    // Thread t writes float4 indices {t, t+256, t+512}: 16B/lane, consecutive
    // lanes -> consecutive addresses. Fully coalesced.
    float4* dp = reinterpret_cast<float4*>(out) + (size_t)blockIdx.x * (3 * BLK);
    dp[t]           = sd[t];
    dp[t + BLK]     = sd[t + BLK];
    dp[t + 2 * BLK] = sd[t + 2 * BLK];
}

extern "C" void kernel_launch(void* const* d_in, const int* in_sizes, int n_in,
                              void* d_out, int out_size, void* d_ws, size_t ws_size,
                              hipStream_t stream) {
    const float* fake = (const float*)d_in[0];   // [B, D]
    const float* minb = (const float*)d_in[1];   // [D]
    const float* lens = (const float*)d_in[2];   // [D, 4]
    float* out = (float*)d_out;                  // dist [B,D,6] then val [B,D]

    const int grid = NP / BLK;                   // 14824, exact
    disc_kernel<<<grid, BLK, 0, stream>>>(fake, minb, lens, out);
}